// Round 3
// baseline (319.257 us; speedup 1.0000x reference)
//
#include <hip/hip_runtime.h>
#include <cstdint>
#include <cstddef>

#define M_TOT 32768   // B*N
#define D_    256
#define DN_   128
#define TWO_D 512
#define H_    1024
#define TWO_H 2048

typedef unsigned short ushort_t;
typedef __attribute__((ext_vector_type(8))) short bf16x8;  // 8 bf16 = 4 VGPRs
typedef __attribute__((ext_vector_type(4))) float f32x4;

__device__ __forceinline__ ushort_t f2bf(float f) {
  union { float f; uint32_t i; } v; v.f = f;
  uint32_t r = v.i + 0x7fffu + ((v.i >> 16) & 1u);
  return (ushort_t)(r >> 16);
}

__device__ __forceinline__ void async_ld16(const void* g, void* l) {
  __builtin_amdgcn_global_load_lds(
      (const __attribute__((address_space(1))) void*)g,
      (__attribute__((address_space(3))) void*)l, 16, 0, 0);
}

// ---------------- tiny cond GEMM: ss[b][j] = ctx[b]·cond_w[:,j] + cond_b[j]  (all f32)
__global__ __launch_bounds__(256) void cond_ss_kernel(
    const float* __restrict__ ctx, const float* __restrict__ cond_w,
    const float* __restrict__ cond_b, float* __restrict__ ss) {
  int j = blockIdx.x * 256 + threadIdx.x;   // 4096 total: b=j>>9, col=j&511
  int b = j >> 9, col = j & 511;
  float acc = cond_b[col];
  for (int k = 0; k < DN_; ++k)
    acc += ctx[b * DN_ + k] * cond_w[k * TWO_D + col];
  ss[j] = acc;
}

// ---------------- tiled transpose: f32 [R][C] -> bf16 [C][R]  (64x64 tiles)
__global__ __launch_bounds__(256) void transpose_f32_bf16_kernel(
    const float* __restrict__ in, ushort_t* __restrict__ out, int R, int C) {
  __shared__ float T[64 * 65];
  int ctiles = C >> 6;
  int bi = blockIdx.x / ctiles, bj = blockIdx.x % ctiles;
  int r0 = bi * 64, c0 = bj * 64;
  int tid = threadIdx.x;
#pragma unroll
  for (int it = 0; it < 16; ++it) {
    int idx = it * 256 + tid;            // 0..4095
    int r = idx >> 6, c = idx & 63;
    T[r * 65 + c] = in[(size_t)(r0 + r) * C + c0 + c];
  }
  __syncthreads();
#pragma unroll
  for (int it = 0; it < 8; ++it) {
    int idx = it * 256 + tid;            // 0..2047
    int a = idx >> 5;                    // in-col -> out row
    int b = (idx & 31) * 2;              // in-row pair -> out col pair
    uint32_t pk = (uint32_t)f2bf(T[b * 65 + a]) |
                  ((uint32_t)f2bf(T[(b + 1) * 65 + a]) << 16);
    *(uint32_t*)&out[(size_t)(c0 + a) * R + r0 + b] = pk;
  }
}

// ---------------- emb gather -> W2T[f*8+o][d] = emb[idx[f]][d*8+o], coalesced 16B writes
__global__ __launch_bounds__(256) void gather_emb_kernel(
    const float* __restrict__ emb, const int* __restrict__ idx,
    ushort_t* __restrict__ W2T) {
  int f = blockIdx.x;                    // 0..127
  // int64-vs-int32 sniff: if idx is int64 (<1024 values), odd words are 0
  bool looks64 = (idx[1] == 0) & (idx[3] == 0) & (idx[5] == 0) & (idx[7] == 0);
  int fi = looks64 ? idx[2 * f] : idx[f];
  const float* src = emb + (size_t)fi * 2048;
  int o = threadIdx.x >> 5, d0 = (threadIdx.x & 31) * 8;
  ushort_t buf[8];
#pragma unroll
  for (int k = 0; k < 8; ++k) buf[k] = f2bf(src[(d0 + k) * 8 + o]);
  *(bf16x8*)&W2T[(size_t)(f * 8 + o) * 256 + d0] = *(bf16x8*)buf;
}

// ---------------- fused LayerNorm + FiLM  (one wave per row of 256), f32 in -> bf16 out
__global__ __launch_bounds__(256) void ln_film_kernel(
    const float* __restrict__ x, const float* __restrict__ ss,
    ushort_t* __restrict__ h) {
  int row = blockIdx.x * 4 + (threadIdx.x >> 6);
  int lane = threadIdx.x & 63;
  int b = row >> 12;
  const float* xr = x + (size_t)row * D_;
  float4 pk = *(const float4*)(xr + lane * 4);
  float f0 = pk.x, f1 = pk.y, f2 = pk.z, f3 = pk.w;
  float s = f0 + f1 + f2 + f3;
  float q = f0 * f0 + f1 * f1 + f2 * f2 + f3 * f3;
#pragma unroll
  for (int off = 32; off > 0; off >>= 1) {
    s += __shfl_xor(s, off, 64);
    q += __shfl_xor(q, off, 64);
  }
  float mean = s * (1.0f / 256.0f);
  float var = q * (1.0f / 256.0f) - mean * mean;
  float rs = rsqrtf(var + 1e-5f);
  int d = lane * 4;
  const float* ssb = ss + b * TWO_D;
  float o0 = (f0 - mean) * rs * (1.0f + ssb[d + 0]) + ssb[256 + d + 0];
  float o1 = (f1 - mean) * rs * (1.0f + ssb[d + 1]) + ssb[256 + d + 1];
  float o2 = (f2 - mean) * rs * (1.0f + ssb[d + 2]) + ssb[256 + d + 2];
  float o3 = (f3 - mean) * rs * (1.0f + ssb[d + 3]) + ssb[256 + d + 3];
  uint2 st;
  st.x = (uint32_t)f2bf(o0) | ((uint32_t)f2bf(o1) << 16);
  st.y = (uint32_t)f2bf(o2) | ((uint32_t)f2bf(o3) << 16);
  *(uint2*)(h + (size_t)row * D_ + lane * 4) = st;
}

// ---------------- generic GEMM: C[M][N] = A[M][K] * BT[N][K]^T (+f32 bias)
// 128x128 tile, BK=32, 4 waves (2x2), 16x16x32 MFMA.
// Epilogue: LDS round-trip (two 64-row passes) -> coalesced float4 / packed-bf16 stores.
template <bool BIAS, bool OUT_F32>
__global__ __launch_bounds__(256, 2) void gemm_bt_kernel(
    const ushort_t* __restrict__ A, const ushort_t* __restrict__ BT,
    const float* __restrict__ bias, void* __restrict__ Cout,
    int M, int N, int K) {
  __shared__ ushort_t As[128 * 32];
  __shared__ ushort_t Bs[128 * 32];
  __shared__ float Cs[64 * 132];   // 64 rows x 128 cols, stride 132 (pad: 4-row stride -> 2-way only)
  const int tid = threadIdx.x, lane = tid & 63, wave = tid >> 6;
  const int wm = wave >> 1, wn = wave & 1;
  const int m0 = blockIdx.x * 128, n0 = blockIdx.y * 128;
  const int srow = lane >> 2, sch = (lane & 3) * 8;
  f32x4 acc[4][4] = {};
  for (int k0 = 0; k0 < K; k0 += 32) {
    for (int i = wave; i < 8; i += 4) {
      async_ld16(A + (size_t)(m0 + i * 16 + srow) * K + k0 + sch, &As[i * 512]);
      async_ld16(BT + (size_t)(n0 + i * 16 + srow) * K + k0 + sch, &Bs[i * 512]);
    }
    __syncthreads();
    bf16x8 a[4], b[4];
#pragma unroll
    for (int i = 0; i < 4; ++i)
      a[i] = *(const bf16x8*)&As[(wm * 64 + i * 16 + (lane & 15)) * 32 + (lane >> 4) * 8];
#pragma unroll
    for (int j = 0; j < 4; ++j)
      b[j] = *(const bf16x8*)&Bs[(wn * 64 + j * 16 + (lane & 15)) * 32 + (lane >> 4) * 8];
#pragma unroll
    for (int i = 0; i < 4; ++i)
#pragma unroll
      for (int j = 0; j < 4; ++j)
        acc[i][j] = __builtin_amdgcn_mfma_f32_16x16x32_bf16(a[i], b[j], acc[i][j], 0, 0, 0);
    __syncthreads();
  }
  // epilogue: pass p handles rows [p*64, p*64+64)
#pragma unroll
  for (int p = 0; p < 2; ++p) {
    __syncthreads();
    if (wm == p) {
#pragma unroll
      for (int j = 0; j < 4; ++j) {
        int col = wn * 64 + j * 16 + (lane & 15);
        float bv = BIAS ? bias[n0 + col] : 0.0f;
#pragma unroll
        for (int i = 0; i < 4; ++i) {
          int rl = i * 16 + ((lane >> 4) << 2);
#pragma unroll
          for (int r = 0; r < 4; ++r)
            Cs[(rl + r) * 132 + col] = acc[i][j][r] + bv;
        }
      }
    }
    __syncthreads();
#pragma unroll
    for (int it = 0; it < 8; ++it) {
      int t = it * 256 + tid;            // 0..2047
      int r = t >> 5, c = (t & 31) * 4;  // row 0..63, col 0..124
      float4 v = *(const float4*)&Cs[r * 132 + c];
      size_t off = (size_t)(m0 + p * 64 + r) * N + n0 + c;
      if (OUT_F32) {
        *(float4*)((float*)Cout + off) = v;
      } else {
        ushort4 s4;
        s4.x = f2bf(v.x); s4.y = f2bf(v.y); s4.z = f2bf(v.z); s4.w = f2bf(v.w);
        *(ushort4*)((ushort_t*)Cout + off) = s4;
      }
    }
  }
}

// ---------------- gated in-proj GEMM: g = gelu(h@Wu + bu) * (h@Wv + bv), bf16 out
// block: 128 rows x 64 gate-cols; wave (wm,wn): 64 rows x 32 cols of BOTH u and v
__global__ __launch_bounds__(256, 2) void gemm_gated_kernel(
    const ushort_t* __restrict__ A,     // h [32768][256] bf16
    const ushort_t* __restrict__ WinT,  // [2048][256] bf16; rows [0,1024)=u, [1024,2048)=v
    const float* __restrict__ bin,      // [2048] f32
    ushort_t* __restrict__ G) {         // [32768][1024] bf16
  __shared__ ushort_t As[128 * 32];
  __shared__ ushort_t Bus[64 * 32];
  __shared__ ushort_t Bvs[64 * 32];
  __shared__ float Cs[64 * 68];         // 64 rows x 64 cols, stride 68
  const int tid = threadIdx.x, lane = tid & 63, wave = tid >> 6;
  const int wm = wave >> 1, wn = wave & 1;
  const int m0 = blockIdx.x * 128;
  const int j0 = blockIdx.y * 64;
  const int srow = lane >> 2, sch = (lane & 3) * 8;
  const int K = 256;
  f32x4 au[4][2] = {}, av[4][2] = {};
  for (int k0 = 0; k0 < K; k0 += 32) {
    for (int i = wave; i < 8; i += 4)
      async_ld16(A + (size_t)(m0 + i * 16 + srow) * K + k0 + sch, &As[i * 512]);
    {
      int i = wave;  // 0..3 covers the 64-row B tiles
      async_ld16(WinT + (size_t)(j0 + i * 16 + srow) * K + k0 + sch, &Bus[i * 512]);
      async_ld16(WinT + (size_t)(1024 + j0 + i * 16 + srow) * K + k0 + sch, &Bvs[i * 512]);
    }
    __syncthreads();
    bf16x8 a[4], bu[2], bv[2];
#pragma unroll
    for (int i = 0; i < 4; ++i)
      a[i] = *(const bf16x8*)&As[(wm * 64 + i * 16 + (lane & 15)) * 32 + (lane >> 4) * 8];
#pragma unroll
    for (int j = 0; j < 2; ++j) {
      bu[j] = *(const bf16x8*)&Bus[(wn * 32 + j * 16 + (lane & 15)) * 32 + (lane >> 4) * 8];
      bv[j] = *(const bf16x8*)&Bvs[(wn * 32 + j * 16 + (lane & 15)) * 32 + (lane >> 4) * 8];
    }
#pragma unroll
    for (int i = 0; i < 4; ++i)
#pragma unroll
      for (int j = 0; j < 2; ++j) {
        au[i][j] = __builtin_amdgcn_mfma_f32_16x16x32_bf16(a[i], bu[j], au[i][j], 0, 0, 0);
        av[i][j] = __builtin_amdgcn_mfma_f32_16x16x32_bf16(a[i], bv[j], av[i][j], 0, 0, 0);
      }
    __syncthreads();
  }
  // epilogue: gelu-gate into LDS, then coalesced packed-bf16 stores
#pragma unroll
  for (int p = 0; p < 2; ++p) {
    __syncthreads();
    if (wm == p) {
#pragma unroll
      for (int j = 0; j < 2; ++j) {
        int col = wn * 32 + j * 16 + (lane & 15);
        float bub = bin[j0 + col];
        float bvb = bin[1024 + j0 + col];
#pragma unroll
        for (int i = 0; i < 4; ++i) {
          int rl = i * 16 + ((lane >> 4) << 2);
#pragma unroll
          for (int r = 0; r < 4; ++r) {
            float u = au[i][j][r] + bub;
            float v = av[i][j][r] + bvb;
            // tanh-approx gelu (JAX default approximate=True)
            float t = 0.7978845608028654f * (u + 0.044715f * u * u * u);
            float e = __expf(2.0f * t);
            float th = 1.0f - 2.0f / (e + 1.0f);
            float gl = 0.5f * u * (1.0f + th);
            Cs[(rl + r) * 68 + col] = gl * v;
          }
        }
      }
    }
    __syncthreads();
#pragma unroll
    for (int it = 0; it < 4; ++it) {
      int t = it * 256 + tid;            // 0..1023
      int r = t >> 4, c = (t & 15) * 4;  // row 0..63, col 0..60
      float4 v = *(const float4*)&Cs[r * 68 + c];
      ushort4 s4;
      s4.x = f2bf(v.x); s4.y = f2bf(v.y); s4.z = f2bf(v.z); s4.w = f2bf(v.w);
      *(ushort4*)&G[(size_t)(m0 + p * 64 + r) * 1024 + j0 + c] = s4;
    }
  }
}

extern "C" void kernel_launch(void* const* d_in, const int* in_sizes, int n_in,
                              void* d_out, int out_size, void* d_ws, size_t ws_size,
                              hipStream_t stream) {
  const float* x      = (const float*)d_in[0];
  const float* ctx    = (const float*)d_in[1];
  const int*   idx    = (const int*)d_in[2];
  const float* cond_w = (const float*)d_in[3];
  const float* cond_b = (const float*)d_in[4];
  const float* w_in   = (const float*)d_in[5];
  const float* b_in   = (const float*)d_in[6];
  const float* w_out  = (const float*)d_in[7];
  const float* b_out  = (const float*)d_in[8];
  const float* emb    = (const float*)d_in[9];

  char* w = (char*)d_ws;
  float* ss = (float*)w;           w += (size_t)8 * TWO_D * 4;        // 16 KB
  ushort_t* h = (ushort_t*)w;      w += (size_t)M_TOT * D_ * 2;       // 16.8 MB
  ushort_t* y = (ushort_t*)w;      w += (size_t)M_TOT * D_ * 2;       // 16.8 MB
  ushort_t* WinT = (ushort_t*)w;   w += (size_t)TWO_H * D_ * 2;       // 1 MB
  ushort_t* WoutT = (ushort_t*)w;  w += (size_t)D_ * H_ * 2;          // 0.5 MB
  ushort_t* W2T = (ushort_t*)w;    w += (size_t)H_ * D_ * 2;          // 0.5 MB
  // g (bf16 [32768][1024], 67 MB) parked in the f32 d_out buffer (134 MB);
  // fully rewritten before any read, overwritten by the final f32 GEMM after G2.
  ushort_t* g = (ushort_t*)d_out;

  cond_ss_kernel<<<16, 256, 0, stream>>>(ctx, cond_w, cond_b, ss);
  transpose_f32_bf16_kernel<<<(D_ / 64) * (TWO_H / 64), 256, 0, stream>>>(w_in, WinT, D_, TWO_H);
  transpose_f32_bf16_kernel<<<(H_ / 64) * (D_ / 64), 256, 0, stream>>>(w_out, WoutT, H_, D_);
  gather_emb_kernel<<<128, 256, 0, stream>>>(emb, idx, W2T);
  ln_film_kernel<<<M_TOT / 4, 256, 0, stream>>>(x, ss, h);
  gemm_gated_kernel<<<dim3(256, 16), 256, 0, stream>>>(h, WinT, b_in, g);
  gemm_bt_kernel<true, false><<<dim3(256, 2), 256, 0, stream>>>(g, WoutT, b_out, y, M_TOT, 256, 1024);
  gemm_bt_kernel<false, true><<<dim3(256, 8), 256, 0, stream>>>(y, W2T, nullptr, d_out, M_TOT, 1024, 256);
}

// Round 4
// 307.233 us; speedup vs baseline: 1.0391x; 1.0391x over previous
//
#include <hip/hip_runtime.h>
#include <cstdint>
#include <cstddef>

#define M_TOT 32768   // B*N
#define D_    256
#define DN_   128
#define TWO_D 512
#define H_    1024
#define TWO_H 2048

typedef unsigned short ushort_t;
typedef __attribute__((ext_vector_type(8))) short bf16x8;  // 8 bf16 = 4 VGPRs
typedef __attribute__((ext_vector_type(4))) float f32x4;

__device__ __forceinline__ ushort_t f2bf(float f) {
  union { float f; uint32_t i; } v; v.f = f;
  uint32_t r = v.i + 0x7fffu + ((v.i >> 16) & 1u);
  return (ushort_t)(r >> 16);
}

__device__ __forceinline__ void async_ld16(const void* g, void* l) {
  __builtin_amdgcn_global_load_lds(
      (const __attribute__((address_space(1))) void*)g,
      (__attribute__((address_space(3))) void*)l, 16, 0, 0);
}

// ---------------- tiny cond GEMM: ss[b][j] = ctx[b]·cond_w[:,j] + cond_b[j]  (all f32)
__global__ __launch_bounds__(256) void cond_ss_kernel(
    const float* __restrict__ ctx, const float* __restrict__ cond_w,
    const float* __restrict__ cond_b, float* __restrict__ ss) {
  int j = blockIdx.x * 256 + threadIdx.x;   // 4096 total: b=j>>9, col=j&511
  int b = j >> 9, col = j & 511;
  float acc = cond_b[col];
  for (int k = 0; k < DN_; ++k)
    acc += ctx[b * DN_ + k] * cond_w[k * TWO_D + col];
  ss[j] = acc;
}

// ---------------- tiled transpose: f32 [R][C] -> bf16 [C][R]  (64x64 tiles)
__global__ __launch_bounds__(256) void transpose_f32_bf16_kernel(
    const float* __restrict__ in, ushort_t* __restrict__ out, int R, int C) {
  __shared__ float T[64 * 65];
  int ctiles = C >> 6;
  int bi = blockIdx.x / ctiles, bj = blockIdx.x % ctiles;
  int r0 = bi * 64, c0 = bj * 64;
  int tid = threadIdx.x;
#pragma unroll
  for (int it = 0; it < 16; ++it) {
    int idx = it * 256 + tid;            // 0..4095
    int r = idx >> 6, c = idx & 63;
    T[r * 65 + c] = in[(size_t)(r0 + r) * C + c0 + c];
  }
  __syncthreads();
#pragma unroll
  for (int it = 0; it < 8; ++it) {
    int idx = it * 256 + tid;            // 0..2047
    int a = idx >> 5;                    // in-col -> out row
    int b = (idx & 31) * 2;              // in-row pair -> out col pair
    uint32_t pk = (uint32_t)f2bf(T[b * 65 + a]) |
                  ((uint32_t)f2bf(T[(b + 1) * 65 + a]) << 16);
    *(uint32_t*)&out[(size_t)(c0 + a) * R + r0 + b] = pk;
  }
}

// ---------------- emb gather -> W2T[f*8+o][d] = emb[idx[f]][d*8+o], coalesced 16B writes
__global__ __launch_bounds__(256) void gather_emb_kernel(
    const float* __restrict__ emb, const int* __restrict__ idx,
    ushort_t* __restrict__ W2T) {
  int f = blockIdx.x;                    // 0..127
  // int64-vs-int32 sniff: if idx is int64 (<1024 values), odd words are 0
  bool looks64 = (idx[1] == 0) & (idx[3] == 0) & (idx[5] == 0) & (idx[7] == 0);
  int fi = looks64 ? idx[2 * f] : idx[f];
  const float* src = emb + (size_t)fi * 2048;
  int o = threadIdx.x >> 5, d0 = (threadIdx.x & 31) * 8;
  ushort_t buf[8];
#pragma unroll
  for (int k = 0; k < 8; ++k) buf[k] = f2bf(src[(d0 + k) * 8 + o]);
  *(bf16x8*)&W2T[(size_t)(f * 8 + o) * 256 + d0] = *(bf16x8*)buf;
}

// ---------------- fused LayerNorm + FiLM  (one wave per row of 256), f32 in -> bf16 out
__global__ __launch_bounds__(256) void ln_film_kernel(
    const float* __restrict__ x, const float* __restrict__ ss,
    ushort_t* __restrict__ h) {
  int row = blockIdx.x * 4 + (threadIdx.x >> 6);
  int lane = threadIdx.x & 63;
  int b = row >> 12;
  const float* xr = x + (size_t)row * D_;
  float4 pk = *(const float4*)(xr + lane * 4);
  float f0 = pk.x, f1 = pk.y, f2 = pk.z, f3 = pk.w;
  float s = f0 + f1 + f2 + f3;
  float q = f0 * f0 + f1 * f1 + f2 * f2 + f3 * f3;
#pragma unroll
  for (int off = 32; off > 0; off >>= 1) {
    s += __shfl_xor(s, off, 64);
    q += __shfl_xor(q, off, 64);
  }
  float mean = s * (1.0f / 256.0f);
  float var = q * (1.0f / 256.0f) - mean * mean;
  float rs = rsqrtf(var + 1e-5f);
  int d = lane * 4;
  const float* ssb = ss + b * TWO_D;
  float o0 = (f0 - mean) * rs * (1.0f + ssb[d + 0]) + ssb[256 + d + 0];
  float o1 = (f1 - mean) * rs * (1.0f + ssb[d + 1]) + ssb[256 + d + 1];
  float o2 = (f2 - mean) * rs * (1.0f + ssb[d + 2]) + ssb[256 + d + 2];
  float o3 = (f3 - mean) * rs * (1.0f + ssb[d + 3]) + ssb[256 + d + 3];
  uint2 st;
  st.x = (uint32_t)f2bf(o0) | ((uint32_t)f2bf(o1) << 16);
  st.y = (uint32_t)f2bf(o2) | ((uint32_t)f2bf(o3) << 16);
  *(uint2*)(h + (size_t)row * D_ + lane * 4) = st;
}

// ---------------- fused gated-FFN: y = (gelu(h@Wu+bu)*(h@Wv+bv)) @ Wout + bout
// One block = 64 M-rows. h-tile staged once; loop 16 gate-chunks of 64 cols:
//   gated MFMA (BK=128, 2 staging steps) -> gelu-gate -> g in LDS (per-wave rows,
//   no barrier) -> stage WoutT k-slice -> accumulate y (16 f32x4/thread).
// Wave w owns rows [16w,16w+16) throughout.
__global__ __launch_bounds__(256, 2) void ffn_fused_kernel(
    const ushort_t* __restrict__ h,      // [32768][256] bf16
    const ushort_t* __restrict__ WinT,   // [2048][256] bf16 (u rows 0..1023, v 1024..2047)
    const float* __restrict__ bin,       // [2048] f32
    const ushort_t* __restrict__ WoutT,  // [256][1024] bf16
    const float* __restrict__ bout,      // [256] f32
    ushort_t* __restrict__ y) {          // [32768][256] bf16
  __shared__ ushort_t Ah[64 * 256];      // 32 KB: 32 tiles of 16x32, t = kc*4 + rt
  __shared__ ushort_t Sh[64 * 264];      // 33 KB: staging (32 tiles) / y epilogue (stride 264)
  __shared__ ushort_t Gs[64 * 72];       // 9.2 KB: g chunk, row-major stride 72 (144 B, 16B-aligned)
  const int tid = threadIdx.x, lane = tid & 63, wave = tid >> 6;
  const int r = lane >> 2, q = lane & 3;         // staging lane decomposition
  const int l15 = lane & 15, l4 = lane >> 4;
  const int m0 = blockIdx.x * 64;
  const int fragoff = l15 * 32 + l4 * 8;         // element offset inside a 16x32 tile

  // stage A (h tile) once: tile t = kc*4 + rt  (rt: m-tile 0..3, kc: k-chunk 0..7)
  for (int t = wave; t < 32; t += 4) {
    int rt = t & 3, kc = t >> 2;
    async_ld16(h + (size_t)(m0 + rt * 16 + r) * 256 + kc * 32 + q * 8, &Ah[t * 512]);
  }

  f32x4 yac[16] = {};                    // y: 16 n-tiles of 16 cols

  for (int j = 0; j < 16; ++j) {         // gate chunk: cols [64j, 64j+64)
    f32x4 uac[4] = {}, vac[4] = {};
#pragma unroll
    for (int s = 0; s < 2; ++s) {        // BK=128: k = [128s, 128s+128)
      __syncthreads();                   // Sh free (prev chunk's Wout reads / prev s reads done)
      for (int t = wave; t < 16; t += 4) {         // Bu tiles 0..15, Bv tiles 16..31
        int rt = t & 3, kc = t >> 2;               // rt: gate-col tile, kc: k-chunk
        size_t grow = (size_t)(j * 64 + rt * 16 + r);
        async_ld16(WinT + grow * 256 + s * 128 + kc * 32 + q * 8, &Sh[t * 512]);
        async_ld16(WinT + (grow + 1024) * 256 + s * 128 + kc * 32 + q * 8, &Sh[(16 + t) * 512]);
      }
      __syncthreads();                   // staging complete (incl. Ah on first pass)
#pragma unroll
      for (int ks = 0; ks < 4; ++ks) {   // k-sub of 32
        bf16x8 af = *(const bf16x8*)&Ah[((s * 4 + ks) * 4 + wave) * 512 + fragoff];
#pragma unroll
        for (int jt = 0; jt < 4; ++jt) {
          bf16x8 bu = *(const bf16x8*)&Sh[(ks * 4 + jt) * 512 + fragoff];
          bf16x8 bv = *(const bf16x8*)&Sh[(16 + ks * 4 + jt) * 512 + fragoff];
          uac[jt] = __builtin_amdgcn_mfma_f32_16x16x32_bf16(af, bu, uac[jt], 0, 0, 0);
          vac[jt] = __builtin_amdgcn_mfma_f32_16x16x32_bf16(af, bv, vac[jt], 0, 0, 0);
        }
      }
    }
    // gelu-gate -> Gs (own rows only; same-wave LDS dep, no barrier)
#pragma unroll
    for (int jt = 0; jt < 4; ++jt) {
      int col = jt * 16 + l15;
      float bub = bin[j * 64 + col];
      float bvb = bin[1024 + j * 64 + col];
#pragma unroll
      for (int rr = 0; rr < 4; ++rr) {
        float u = uac[jt][rr] + bub;
        float v = vac[jt][rr] + bvb;
        float t = 0.7978845608028654f * (u + 0.044715f * u * u * u);
        float e = __expf(2.0f * t);
        float th = 1.0f - 2.0f / (e + 1.0f);
        float gl = 0.5f * u * (1.0f + th);
        Gs[(wave * 16 + l4 * 4 + rr) * 72 + col] = f2bf(gl * v);
      }
    }
    __syncthreads();                     // all waves done reading Sh (BuBv)
    for (int t = wave; t < 32; t += 4) { // WoutT slice: tile t = s2*16 + nt
      int nt = t & 15, s2 = t >> 4;
      async_ld16(WoutT + (size_t)(nt * 16 + r) * 1024 + j * 64 + s2 * 32 + q * 8, &Sh[t * 512]);
    }
    __syncthreads();
#pragma unroll
    for (int s2 = 0; s2 < 2; ++s2) {     // K=64 of G2, two 32-subs
      bf16x8 gf = *(const bf16x8*)&Gs[(wave * 16 + l15) * 72 + s2 * 32 + l4 * 8];
#pragma unroll
      for (int nt = 0; nt < 16; ++nt) {
        bf16x8 bw = *(const bf16x8*)&Sh[(s2 * 16 + nt) * 512 + fragoff];
        yac[nt] = __builtin_amdgcn_mfma_f32_16x16x32_bf16(gf, bw, yac[nt], 0, 0, 0);
      }
    }
  }
  // epilogue: y + bout -> bf16 via Sh (stride 264), then vectorized 16B stores
  __syncthreads();
#pragma unroll
  for (int nt = 0; nt < 16; ++nt) {
    int col = nt * 16 + l15;
    float bb = bout[col];
#pragma unroll
    for (int rr = 0; rr < 4; ++rr)
      Sh[(wave * 16 + l4 * 4 + rr) * 264 + col] = f2bf(yac[nt][rr] + bb);
  }
  __syncthreads();
#pragma unroll
  for (int it = 0; it < 8; ++it) {
    int id = it * 256 + tid;             // 0..2047: rr = row, cc = 8-col chunk
    int rr = id >> 5, cc = id & 31;
    bf16x8 vv = *(const bf16x8*)&Sh[rr * 264 + cc * 8];
    *(bf16x8*)&y[(size_t)(m0 + rr) * 256 + cc * 8] = vv;
  }
}

// ---------------- out GEMM: out[M][1024] = y[M][256] @ W2T[1024][256]^T, f32 out
// 128x128 tile, BK=64 (4 iters), 4 waves (2x2), LDS-roundtrip f32x4 epilogue.
__global__ __launch_bounds__(256, 2) void gemm_out_kernel(
    const ushort_t* __restrict__ A, const ushort_t* __restrict__ BT,
    float* __restrict__ C) {
  __shared__ ushort_t As[128 * 64];      // 16 tiles of 16x32: t = rt*2 + ks
  __shared__ ushort_t Bs[128 * 64];
  __shared__ float Cs[64 * 132];
  const int tid = threadIdx.x, lane = tid & 63, wave = tid >> 6;
  const int wm = wave >> 1, wn = wave & 1;
  const int m0 = blockIdx.x * 128, n0 = blockIdx.y * 128;
  const int r = lane >> 2, q = lane & 3;
  const int l15 = lane & 15, l4 = lane >> 4;
  const int fragoff = l15 * 32 + l4 * 8;
  const int N = 1024, K = 256;
  f32x4 acc[4][4] = {};
  for (int k0 = 0; k0 < K; k0 += 64) {
    for (int t = wave; t < 16; t += 4) {
      int rt = t >> 1, ks = t & 1;
      async_ld16(A + (size_t)(m0 + rt * 16 + r) * K + k0 + ks * 32 + q * 8, &As[t * 512]);
      async_ld16(BT + (size_t)(n0 + rt * 16 + r) * K + k0 + ks * 32 + q * 8, &Bs[t * 512]);
    }
    __syncthreads();
#pragma unroll
    for (int ks = 0; ks < 2; ++ks) {
      bf16x8 a[4], b[4];
#pragma unroll
      for (int i = 0; i < 4; ++i)
        a[i] = *(const bf16x8*)&As[((wm * 4 + i) * 2 + ks) * 512 + fragoff];
#pragma unroll
      for (int jt = 0; jt < 4; ++jt)
        b[jt] = *(const bf16x8*)&Bs[((wn * 4 + jt) * 2 + ks) * 512 + fragoff];
#pragma unroll
      for (int i = 0; i < 4; ++i)
#pragma unroll
        for (int jt = 0; jt < 4; ++jt)
          acc[i][jt] = __builtin_amdgcn_mfma_f32_16x16x32_bf16(a[i], b[jt], acc[i][jt], 0, 0, 0);
    }
    __syncthreads();
  }
#pragma unroll
  for (int p = 0; p < 2; ++p) {
    __syncthreads();
    if (wm == p) {
#pragma unroll
      for (int jt = 0; jt < 4; ++jt) {
        int col = wn * 64 + jt * 16 + l15;
#pragma unroll
        for (int i = 0; i < 4; ++i) {
          int rl = i * 16 + (l4 << 2);
#pragma unroll
          for (int rr = 0; rr < 4; ++rr)
            Cs[(rl + rr) * 132 + col] = acc[i][jt][rr];
        }
      }
    }
    __syncthreads();
#pragma unroll
    for (int it = 0; it < 8; ++it) {
      int t = it * 256 + tid;            // 0..2047
      int rr = t >> 5, c = (t & 31) * 4; // row 0..63, col 0..124
      float4 v = *(const float4*)&Cs[rr * 132 + c];
      *(float4*)&C[(size_t)(m0 + p * 64 + rr) * N + n0 + c] = v;
    }
  }
}

extern "C" void kernel_launch(void* const* d_in, const int* in_sizes, int n_in,
                              void* d_out, int out_size, void* d_ws, size_t ws_size,
                              hipStream_t stream) {
  const float* x      = (const float*)d_in[0];
  const float* ctx    = (const float*)d_in[1];
  const int*   idx    = (const int*)d_in[2];
  const float* cond_w = (const float*)d_in[3];
  const float* cond_b = (const float*)d_in[4];
  const float* w_in   = (const float*)d_in[5];
  const float* b_in   = (const float*)d_in[6];
  const float* w_out  = (const float*)d_in[7];
  const float* b_out  = (const float*)d_in[8];
  const float* emb    = (const float*)d_in[9];

  char* w = (char*)d_ws;
  float* ss = (float*)w;           w += (size_t)8 * TWO_D * 4;        // 16 KB
  ushort_t* h = (ushort_t*)w;      w += (size_t)M_TOT * D_ * 2;       // 16.8 MB
  ushort_t* y = (ushort_t*)w;      w += (size_t)M_TOT * D_ * 2;       // 16.8 MB
  ushort_t* WinT = (ushort_t*)w;   w += (size_t)TWO_H * D_ * 2;       // 1 MB
  ushort_t* WoutT = (ushort_t*)w;  w += (size_t)D_ * H_ * 2;          // 0.5 MB
  ushort_t* W2T = (ushort_t*)w;    w += (size_t)H_ * D_ * 2;          // 0.5 MB

  cond_ss_kernel<<<16, 256, 0, stream>>>(ctx, cond_w, cond_b, ss);
  transpose_f32_bf16_kernel<<<(D_ / 64) * (TWO_H / 64), 256, 0, stream>>>(w_in, WinT, D_, TWO_H);
  transpose_f32_bf16_kernel<<<(H_ / 64) * (D_ / 64), 256, 0, stream>>>(w_out, WoutT, H_, D_);
  gather_emb_kernel<<<128, 256, 0, stream>>>(emb, idx, W2T);
  ln_film_kernel<<<M_TOT / 4, 256, 0, stream>>>(x, ss, h);
  ffn_fused_kernel<<<M_TOT / 64, 256, 0, stream>>>(h, WinT, b_in, WoutT, b_out, y);
  gemm_out_kernel<<<dim3(M_TOT / 128, H_ / 128), 256, 0, stream>>>(y, W2T, (float*)d_out);
}